// Round 7
// baseline (164.856 us; speedup 1.0000x reference)
//
#include <hip/hip_runtime.h>
#include <hip/hip_bf16.h>

#define NFEAT 50
#define EDIM 64
#define LN_EPS 1e-5f
#define NEG_INF_C (-1000000000.0f)
#define NB 4

typedef __bf16 bf16_t;
typedef __bf16 bf16x8 __attribute__((ext_vector_type(8)));
typedef __bf16 bf16x4 __attribute__((ext_vector_type(4)));
typedef float f32x4 __attribute__((ext_vector_type(4)));

#define MFMA __builtin_amdgcn_mfma_f32_16x16x32_bf16

// LDS-only barrier: publishes ds ops (lgkmcnt 0) but leaves global loads/stores
// in flight across the barrier (T4 counted-vmcnt pattern; __syncthreads would
// force vmcnt(0) and drain the cross-iteration feat prefetch every batch).
__device__ __forceinline__ void lds_barrier() {
  asm volatile("s_waitcnt lgkmcnt(0)" ::: "memory");
  __builtin_amdgcn_sched_barrier(0);
  __builtin_amdgcn_s_barrier();
  __builtin_amdgcn_sched_barrier(0);
}

// ws layout:
//   attnT: bf16 [T][64][64], attnT[t][g][f] = attn[t][f][g], zero padded
//   WT:    bf16 [T][2][64][64] XOR-SWIZZLED (chunk c at row e holds k=(c^(e&7))*8+j)
//   tbT:   f32  [T][64][64], tbT[t][e][f] = tb[t][f][e], zero padded
//   attnF: f32  [T][64][64], attnF[t][f][g] = attn[t][f][g], zero padded
//   G:     f32  [T][64][64], G[t][f][k]: gate logit_t = <F_b, G_t> + cst_t + gb
//   cst:   f32  [T], cst[t] = sum tb_t*gw

__global__ __launch_bounds__(256) void prep_kernel(
    const float* __restrict__ masker, const float* __restrict__ ln_w,
    const float* __restrict__ ln_b, const float* __restrict__ tw,
    const float* __restrict__ tb, const float* __restrict__ gw,
    bf16_t* __restrict__ ws_attnT, bf16_t* __restrict__ ws_WT,
    float* __restrict__ ws_tbT, float* __restrict__ ws_attnF,
    float* __restrict__ ws_cst)
{
  __shared__ float red[2][4];
  const int tid = threadIdx.x;
  const int lane = tid & 63;
  const int gidx = blockIdx.x * 256 + tid;   // 0..4095

  // ---- WT staging (swizzled): 16384 elems, 4/thread ----
#pragma unroll
  for (int j = 0; j < 4; ++j) {
    int o = gidx * 4 + j;            // ((ti*64 + e)*64 + kl)
    int kl = o & 63;
    int e = (o >> 6) & 63;
    int ti = o >> 12;
    int k = ((kl >> 3) ^ (e & 7)) * 8 + (kl & 7);
    ws_WT[o] = (bf16_t)tw[(ti * 64 + k) * 64 + e];
  }

  // ---- tbT staging: 8192 elems, 2/thread ----
#pragma unroll
  for (int j = 0; j < 2; ++j) {
    int o = gidx * 2 + j;            // (t*64 + e)*64 + f
    int f = o & 63;
    int e = (o >> 6) & 63;
    int t = o >> 12;
    ws_tbT[o] = (f < NFEAT) ? tb[(t * NFEAT + f) * EDIM + e] : 0.f;
  }

  // ---- gate-bias constants: cst[t] = sum tb_t * gw (block 0 only) ----
  if (blockIdx.x == 0) {
    float s0 = 0.f, s1 = 0.f;
    for (int i = tid; i < NFEAT * EDIM; i += 256) {
      float g = gw[i];
      s0 += tb[i] * g;
      s1 += tb[NFEAT * EDIM + i] * g;
    }
    for (int off = 32; off > 0; off >>= 1) {
      s0 += __shfl_xor(s0, off);
      s1 += __shfl_xor(s1, off);
    }
    if (lane == 0) { red[0][tid >> 6] = s0; red[1][tid >> 6] = s1; }
    __syncthreads();
    if (tid == 0) {
      ws_cst[0] = red[0][0] + red[0][1] + red[0][2] + red[0][3];
      ws_cst[1] = red[1][0] + red[1][1] + red[1][2] + red[1][3];
    }
  }

  // ---- attention columns: 128 tasks (t,g) over 64 waves, 2 each ----
  const int wg = blockIdx.x * 4 + (tid >> 6);  // 0..63
  const int f = lane;
  const bool fv = (f < NFEAT);
  for (int i = 0; i < 2; ++i) {
    int col = wg * 2 + i;            // 0..127
    int t = col >> 6, g = col & 63;
    float val = 0.f;
    if (fv && g < NFEAT) {
      float a0 = masker[((t * 3 + 0) * NFEAT + f) * NFEAT + g];
      float a1 = masker[((t * 3 + 1) * NFEAT + f) * NFEAT + g];
      float a2 = masker[((t * 3 + 2) * NFEAT + f) * NFEAT + g];
      float prod = a0 * a1 * a2;
      val = prod > 0.f ? prod : 0.f;            // relu
    }
    float s = val;
    for (int off = 32; off > 0; off >>= 1) s += __shfl_xor(s, off);
    float mean = s / (float)NFEAT;
    float d = fv ? (val - mean) : 0.f;
    float v2 = d * d;
    for (int off = 32; off > 0; off >>= 1) v2 += __shfl_xor(v2, off);
    float var = v2 / (float)NFEAT;
    float lw = fv ? ln_w[f] : 0.f;
    float lb = fv ? ln_b[f] : 0.f;
    float aln = d * rsqrtf(var + LN_EPS) * lw + lb;
    float logit = aln + ((val != 0.f) ? 0.f : NEG_INF_C) + ((f == g) ? 1.f : 0.f);
    if (!fv) logit = -3.0e38f;
    float mx = logit;
    for (int off = 32; off > 0; off >>= 1) mx = fmaxf(mx, __shfl_xor(mx, off));
    float ex = fv ? expf(logit - mx) : 0.f;
    float se = ex;
    for (int off = 32; off > 0; off >>= 1) se += __shfl_xor(se, off);
    float attn = (fv && g < NFEAT && val != 0.f) ? (ex / se) : 0.f;
    ws_attnT[(t * 64 + g) * 64 + f] = (bf16_t)attn;
    ws_attnF[(t * 64 + f) * 64 + g] = attn;    // f-major copy for prep2
  }
}

// prep2 (R5-verified): G_t[f][k] = V + Y,  V[f,k]=sum_e gw[f,e]W1_t[k,e],
// Y[f,k]=sum_g attn_t[f,g]*R[g,k], R[g,k]=sum_e gw[g,e]W2_t[k,e].
__global__ __launch_bounds__(256) void prep2_kernel(
    const float* __restrict__ tw, const float* __restrict__ gw,
    const float* __restrict__ ws_attnF, float* __restrict__ ws_G)
{
  __shared__ bf16_t sRT[64 * 72];   // R^T[k][g], pitch 72
  const int t = blockIdx.x;
  const int tid = threadIdx.x;
  const int w = tid >> 6;
  const int lane = tid & 63;
  const int l16 = lane & 15;
  const int lquad = lane >> 4;
  const int fr = w * 16 + l16;
  const bool frv = (fr < NFEAT);

  // A-frags from gw rows fr
  bf16x8 ag[2];
#pragma unroll
  for (int kc = 0; kc < 2; ++kc) {
#pragma unroll
    for (int j = 0; j < 8; ++j) ag[kc][j] = (bf16_t)0.f;
    if (frv) {
      const float* p = gw + fr * 64 + kc * 32 + lquad * 8;
      const f32x4 r0 = *(const f32x4*)(p);
      const f32x4 r1 = *(const f32x4*)(p + 4);
#pragma unroll
      for (int j = 0; j < 4; ++j) { ag[kc][j] = (bf16_t)r0[j]; ag[kc][j+4] = (bf16_t)r1[j]; }
    }
  }

  // R pass
  f32x4 accR[4];
#pragma unroll
  for (int n = 0; n < 4; ++n) accR[n] = (f32x4){0.f,0.f,0.f,0.f};
#pragma unroll
  for (int kc = 0; kc < 2; ++kc)
#pragma unroll
    for (int n = 0; n < 4; ++n) {
      const float* p = tw + ((2*t+1)*64 + n*16 + l16) * 64 + kc*32 + lquad*8;
      const f32x4 r0 = *(const f32x4*)(p);
      const f32x4 r1 = *(const f32x4*)(p + 4);
      bf16x8 bw;
#pragma unroll
      for (int j = 0; j < 4; ++j) { bw[j] = (bf16_t)r0[j]; bw[j+4] = (bf16_t)r1[j]; }
      accR[n] = MFMA(ag[kc], bw, accR[n], 0, 0, 0);
    }
#pragma unroll
  for (int n = 0; n < 4; ++n) {
    bf16x4 pv;
    pv[0]=(bf16_t)accR[n][0]; pv[1]=(bf16_t)accR[n][1];
    pv[2]=(bf16_t)accR[n][2]; pv[3]=(bf16_t)accR[n][3];
    *(bf16x4*)&sRT[(n*16 + l16) * 72 + w*16 + lquad*4] = pv;
  }

  // V pass
  f32x4 acc[4];
#pragma unroll
  for (int n = 0; n < 4; ++n) acc[n] = (f32x4){0.f,0.f,0.f,0.f};
#pragma unroll
  for (int kc = 0; kc < 2; ++kc)
#pragma unroll
    for (int n = 0; n < 4; ++n) {
      const float* p = tw + ((2*t)*64 + n*16 + l16) * 64 + kc*32 + lquad*8;
      const f32x4 r0 = *(const f32x4*)(p);
      const f32x4 r1 = *(const f32x4*)(p + 4);
      bf16x8 bw;
#pragma unroll
      for (int j = 0; j < 4; ++j) { bw[j] = (bf16_t)r0[j]; bw[j+4] = (bf16_t)r1[j]; }
      acc[n] = MFMA(ag[kc], bw, acc[n], 0, 0, 0);
    }

  __syncthreads();   // sRT ready

  // Y pass
  bf16x8 aa[2];
#pragma unroll
  for (int kc = 0; kc < 2; ++kc) {
    const float* p = ws_attnF + (t*64 + fr) * 64 + kc*32 + lquad*8;
    const f32x4 r0 = *(const f32x4*)(p);
    const f32x4 r1 = *(const f32x4*)(p + 4);
#pragma unroll
    for (int j = 0; j < 4; ++j) { aa[kc][j] = (bf16_t)r0[j]; aa[kc][j+4] = (bf16_t)r1[j]; }
  }
#pragma unroll
  for (int kc = 0; kc < 2; ++kc)
#pragma unroll
    for (int n = 0; n < 4; ++n) {
      const bf16x8 bp = *(const bf16x8*)(&sRT[(n*16 + l16) * 72 + kc*32 + lquad*8]);
      acc[n] = MFMA(aa[kc], bp, acc[n], 0, 0, 0);
    }

#pragma unroll
  for (int n = 0; n < 4; ++n)
#pragma unroll
    for (int r = 0; r < 4; ++r)
      ws_G[t*4096 + (w*16 + lquad*4 + r) * 64 + n*16 + l16] = acc[n][r];
}

// R6 champion structure + round-7 deltas:
//  (1) lds_barrier (lgkmcnt-only) instead of __syncthreads: feat prefetch
//      issued before pass1 stays in flight across BOTH barriers, consumed
//      next batch (~1000cy cover vs 900cy HBM latency).
//  (2) G-linearized gate: logit_t = <F_b,G_t>+cst_t computed from raw feat
//      BEFORE pass1 (shfl-reduce hides under MFMA completion); B1->B2 segment
//      is pure pass2; epilogue needs no post-B2 reduce.
__global__ __launch_bounds__(256) void main_kernel(
    const float* __restrict__ feat, const float* __restrict__ gb,
    const bf16_t* __restrict__ ws_attnT, const bf16_t* __restrict__ ws_WT,
    const float* __restrict__ ws_tbT, const float* __restrict__ ws_G,
    const float* __restrict__ ws_cst,
    float* __restrict__ out)
{
  __shared__ bf16_t sWT[4 * 64 * 64];  // 32 KB swizzled
  __shared__ bf16_t sPT[2][64 * 64];   // 16 KB swizzled P^T per t
  __shared__ float sLog[2][4];

  const int tid = threadIdx.x;
  const int w = tid >> 6;
  const int lane = tid & 63;
  const int l16 = lane & 15;
  const int lquad = lane >> 4;
  const int m0 = w * 16;

  // ---- stage WT into LDS (linear copy; global is pre-swizzled) ----
#pragma unroll
  for (int it = 0; it < 8; ++it) {
    const int idx = it * 256 + tid;
    *(bf16x8*)&sWT[idx * 8] = *(const bf16x8*)(ws_WT + idx * 8);
  }

  // ---- block-invariant register state ----
  bf16x8 aat[2][2];
#pragma unroll
  for (int t = 0; t < 2; ++t)
#pragma unroll
    for (int kc = 0; kc < 2; ++kc)
      aat[t][kc] = *(const bf16x8*)(ws_attnT + (t * 64 + m0 + l16) * 64 + kc * 32 + lquad * 8);

  const float cst0 = ws_cst[0], cst1 = ws_cst[1], gbv = gb[0];
  const int fA = m0 + l16;
  const bool fAv = (fA < NFEAT);
  const int b0 = blockIdx.x * NB;
  const int foff = fA * 64 + lquad * 8;
  const int exl = l16 & 7;
  const int wcl = (m0 >> 3) + (lquad >> 1);
  const int whf = (lquad & 1) * 4;

  // persistent G-frags: G_t[fA, cols matching raw] (rows >=50 are zero)
  f32x4 gfr[2][4];
#pragma unroll
  for (int t = 0; t < 2; ++t) {
    const float* gp = ws_G + t * 4096 + foff;
    gfr[t][0] = *(const f32x4*)(gp);
    gfr[t][1] = *(const f32x4*)(gp + 4);
    gfr[t][2] = *(const f32x4*)(gp + 32);
    gfr[t][3] = *(const f32x4*)(gp + 36);
  }

  // ---- prefetch feat for ib = 0 (stays in flight across staging barrier) ----
  f32x4 raw[4];
#pragma unroll
  for (int i = 0; i < 4; ++i) raw[i] = (f32x4){0.f, 0.f, 0.f, 0.f};
  if (fAv) {
    const float* fb = feat + b0 * (NFEAT * EDIM) + foff;
    raw[0] = *(const f32x4*)(fb);
    raw[1] = *(const f32x4*)(fb + 4);
    raw[2] = *(const f32x4*)(fb + 32);
    raw[3] = *(const f32x4*)(fb + 36);
  }

  lds_barrier();                       // sWT ready (feat loads NOT drained)

#pragma unroll 1
  for (int ib = 0; ib < NB; ++ib) {
    const int b = b0 + ib;

    // ---- convert prefetched raw -> bf16 A-frags ----
    bf16x8 a[2];
#pragma unroll
    for (int kc = 0; kc < 2; ++kc)
#pragma unroll
      for (int j = 0; j < 8; ++j) a[kc][j] = (bf16_t)0.f;
    if (fAv) {
#pragma unroll
      for (int j = 0; j < 4; ++j) {
        a[0][j] = (bf16_t)raw[0][j]; a[0][j + 4] = (bf16_t)raw[1][j];
        a[1][j] = (bf16_t)raw[2][j]; a[1][j + 4] = (bf16_t)raw[3][j];
      }
    }

    // ---- gate partials from raw x G (VALU; overlaps pass1 MFMA) ----
    float p0 = 0.f, p1 = 0.f;
#pragma unroll
    for (int q = 0; q < 4; ++q)
#pragma unroll
      for (int j = 0; j < 4; ++j) {
        p0 += raw[q][j] * gfr[0][q][j];
        p1 += raw[q][j] * gfr[1][q][j];
      }

    // ---- prefetch next batch's feat (raw consumed; crosses B1 AND B2) ----
    if (ib + 1 < NB && fAv) {
      const float* fb = feat + (b + 1) * (NFEAT * EDIM) + foff;
      raw[0] = *(const f32x4*)(fb);
      raw[1] = *(const f32x4*)(fb + 4);
      raw[2] = *(const f32x4*)(fb + 32);
      raw[3] = *(const f32x4*)(fb + 36);
    }

    f32x4 accH[2][4], accP[2][4];
#pragma unroll
    for (int t = 0; t < 2; ++t)
#pragma unroll
      for (int n = 0; n < 4; ++n) {
        accH[t][n] = (f32x4){0.f, 0.f, 0.f, 0.f};
        accP[t][n] = (f32x4){0.f, 0.f, 0.f, 0.f};
      }

    // ---- pass 1: B-frags from sWT (swizzled), 4 indep MFMA streams ----
#pragma unroll
    for (int kc = 0; kc < 2; ++kc) {
      const int co = ((kc * 4 + lquad) ^ exl) * 8;
#pragma unroll
      for (int n = 0; n < 4; ++n) {
        const int ro = (n * 16 + l16) * 64 + co;
        const bf16x8 b10 = *(const bf16x8*)(&sWT[0 * 4096 + ro]);
        const bf16x8 b20 = *(const bf16x8*)(&sWT[1 * 4096 + ro]);
        const bf16x8 b11 = *(const bf16x8*)(&sWT[2 * 4096 + ro]);
        const bf16x8 b21 = *(const bf16x8*)(&sWT[3 * 4096 + ro]);
        accH[0][n] = MFMA(a[kc], b10, accH[0][n], 0, 0, 0);
        accP[0][n] = MFMA(a[kc], b20, accP[0][n], 0, 0, 0);
        accH[1][n] = MFMA(a[kc], b11, accH[1][n], 0, 0, 0);
        accP[1][n] = MFMA(a[kc], b21, accP[1][n], 0, 0, 0);
      }
    }

    // ---- shfl-reduce gate partials (hides under MFMA completion) ----
#pragma unroll
    for (int off = 32; off > 0; off >>= 1) {
      p0 += __shfl_xor(p0, off);
      p1 += __shfl_xor(p1, off);
    }
    if (lane == 0) { sLog[0][w] = p0; sLog[1][w] = p1; }

    // ---- write both P^T tiles (swizzled) ----
#pragma unroll
    for (int t = 0; t < 2; ++t)
#pragma unroll
      for (int n = 0; n < 4; ++n) {
        bf16x4 pv;
        pv[0] = (bf16_t)accP[t][n][0]; pv[1] = (bf16_t)accP[t][n][1];
        pv[2] = (bf16_t)accP[t][n][2]; pv[3] = (bf16_t)accP[t][n][3];
        *(bf16x4*)&sPT[t][(n * 16 + l16) * 64 + ((wcl ^ exl) << 3) + whf] = pv;
      }

    lds_barrier();   // B1: sPT + sLog published (global loads stay in flight)

    // ---- gates (sLog complete after B1) ----
    const float g0 = sLog[0][0] + sLog[0][1] + sLog[0][2] + sLog[0][3] + cst0 + gbv;
    const float g1 = sLog[1][0] + sLog[1][1] + sLog[1][2] + sLog[1][3] + cst1 + gbv;
    const float mx = fmaxf(g0, g1);
    const float e0 = expf(g0 - mx), e1 = expf(g1 - mx);
    const float inv = 1.f / (e0 + e1);
    const float ga0 = e0 * inv, ga1 = e1 * inv;

    // ---- pass 2: accH[t] += attnT_t @ P_t ----
#pragma unroll
    for (int kc = 0; kc < 2; ++kc) {
      const int so0 = ((kc * 4 + lquad) ^ exl) << 3;
#pragma unroll
      for (int n = 0; n < 4; ++n) {
        const int so = (n * 16 + l16) * 64 + so0;
        const bf16x8 bp0 = *(const bf16x8*)(&sPT[0][so]);
        const bf16x8 bp1 = *(const bf16x8*)(&sPT[1][so]);
        accH[0][n] = MFMA(aat[0][kc], bp0, accH[0][n], 0, 0, 0);
        accH[1][n] = MFMA(aat[1][kc], bp1, accH[1][n], 0, 0, 0);
      }
    }

    lds_barrier();   // B2: sPT reads retired; next iter may overwrite

    // ---- epilogue: +tb, gate-combine, store (overlaps next pass1) ----
    float* outb = out + b * (NFEAT * EDIM);
#pragma unroll
    for (int n = 0; n < 4; ++n) {
      const int ro = (n * 16 + l16) * 64 + m0 + lquad * 4;
      const f32x4 tbv0 = *(const f32x4*)(ws_tbT + ro);
      const f32x4 tbv1 = *(const f32x4*)(ws_tbT + 64 * 64 + ro);
      const int e = n * 16 + l16;
#pragma unroll
      for (int r = 0; r < 4; ++r) {
        const int f = m0 + lquad * 4 + r;
        if (f < NFEAT)
          outb[f * 64 + e] = ga0 * (accH[0][n][r] + tbv0[r])
                           + ga1 * (accH[1][n][r] + tbv1[r]);
      }
    }
  }
}

extern "C" void kernel_launch(void* const* d_in, const int* in_sizes, int n_in,
                              void* d_out, int out_size, void* d_ws, size_t ws_size,
                              hipStream_t stream) {
  const float* feat   = (const float*)d_in[0];
  const float* masker = (const float*)d_in[1];
  const float* tw     = (const float*)d_in[2];
  const float* tb     = (const float*)d_in[3];
  const float* lnw    = (const float*)d_in[4];
  const float* lnb    = (const float*)d_in[5];
  const float* gw     = (const float*)d_in[6];
  const float* gb     = (const float*)d_in[7];
  float* out = (float*)d_out;

  bf16_t* ws_attnT = (bf16_t*)d_ws;                  // 8192 bf16
  bf16_t* ws_WT    = ws_attnT + 8192;                // 16384 bf16
  float*  ws_tbT   = (float*)(ws_WT + 16384);        // 8192 f32
  float*  ws_attnF = ws_tbT + 8192;                  // 8192 f32
  float*  ws_G     = ws_attnF + 8192;                // 8192 f32
  float*  ws_cst   = ws_G + 8192;                    // 2 f32

  prep_kernel<<<16, 256, 0, stream>>>(masker, lnw, lnb, tw, tb, gw,
                                      ws_attnT, ws_WT, ws_tbT, ws_attnF, ws_cst);
  prep2_kernel<<<2, 256, 0, stream>>>(tw, gw, ws_attnF, ws_G);
  main_kernel<<<4096 / NB, 256, 0, stream>>>(feat, gb, ws_attnT, ws_WT,
                                             ws_tbT, ws_G, ws_cst, out);
}

// Round 8
// 162.337 us; speedup vs baseline: 1.0155x; 1.0155x over previous
//
#include <hip/hip_runtime.h>
#include <hip/hip_bf16.h>

#define NFEAT 50
#define EDIM 64
#define LN_EPS 1e-5f
#define NEG_INF_C (-1000000000.0f)
#define NBW 2   // batches per wave

typedef __bf16 bf16_t;
typedef __bf16 bf16x8 __attribute__((ext_vector_type(8)));
typedef __bf16 bf16x4 __attribute__((ext_vector_type(4)));
typedef float f32x4 __attribute__((ext_vector_type(4)));

#define MFMA __builtin_amdgcn_mfma_f32_16x16x32_bf16

// ws layout:
//   attnTs: bf16 [T][64][64] A-frag-ready attnT, XOR-swizzled within each row
//           (chunk c at row (t*64+g) holds f = (c^(g&7))*8+j), zero padded
//   WT:     bf16 [T][2][64][64] XOR-SWIZZLED (chunk c at row e holds k=(c^(e&7))*8+j)
//   tbT:    f32  [T][64][64], tbT[t][e][f] = tb[t][f][e], zero padded
//   attnF:  f32  [T][64][64], attnF[t][f][g] = attn[t][f][g], zero padded
//   G:      f32  [T][64][64], G[t][f][k]: gate logit_t = <F_b, G_t> + cst_t + gb
//   cst:    f32  [T], cst[t] = sum tb_t*gw

__global__ __launch_bounds__(256) void prep_kernel(
    const float* __restrict__ masker, const float* __restrict__ ln_w,
    const float* __restrict__ ln_b, const float* __restrict__ tw,
    const float* __restrict__ tb, const float* __restrict__ gw,
    bf16_t* __restrict__ ws_attnTs, bf16_t* __restrict__ ws_WT,
    float* __restrict__ ws_tbT, float* __restrict__ ws_attnF,
    float* __restrict__ ws_cst)
{
  __shared__ float red[2][4];
  const int tid = threadIdx.x;
  const int lane = tid & 63;
  const int gidx = blockIdx.x * 256 + tid;   // 0..4095

  // ---- WT staging (swizzled): 16384 elems, 4/thread ----
#pragma unroll
  for (int j = 0; j < 4; ++j) {
    int o = gidx * 4 + j;            // ((ti*64 + e)*64 + kl)
    int kl = o & 63;
    int e = (o >> 6) & 63;
    int ti = o >> 12;
    int k = ((kl >> 3) ^ (e & 7)) * 8 + (kl & 7);
    ws_WT[o] = (bf16_t)tw[(ti * 64 + k) * 64 + e];
  }

  // ---- tbT staging: 8192 elems, 2/thread ----
#pragma unroll
  for (int j = 0; j < 2; ++j) {
    int o = gidx * 2 + j;            // (t*64 + e)*64 + f
    int f = o & 63;
    int e = (o >> 6) & 63;
    int t = o >> 12;
    ws_tbT[o] = (f < NFEAT) ? tb[(t * NFEAT + f) * EDIM + e] : 0.f;
  }

  // ---- gate-bias constants: cst[t] = sum tb_t * gw (block 0 only) ----
  if (blockIdx.x == 0) {
    float s0 = 0.f, s1 = 0.f;
    for (int i = tid; i < NFEAT * EDIM; i += 256) {
      float g = gw[i];
      s0 += tb[i] * g;
      s1 += tb[NFEAT * EDIM + i] * g;
    }
    for (int off = 32; off > 0; off >>= 1) {
      s0 += __shfl_xor(s0, off);
      s1 += __shfl_xor(s1, off);
    }
    if (lane == 0) { red[0][tid >> 6] = s0; red[1][tid >> 6] = s1; }
    __syncthreads();
    if (tid == 0) {
      ws_cst[0] = red[0][0] + red[0][1] + red[0][2] + red[0][3];
      ws_cst[1] = red[1][0] + red[1][1] + red[1][2] + red[1][3];
    }
  }

  // ---- attention columns: 128 tasks (t,g) over 64 waves, 2 each ----
  const int wg = blockIdx.x * 4 + (tid >> 6);  // 0..63
  const int f = lane;
  const bool fv = (f < NFEAT);
  for (int i = 0; i < 2; ++i) {
    int col = wg * 2 + i;            // 0..127
    int t = col >> 6, g = col & 63;
    float val = 0.f;
    if (fv && g < NFEAT) {
      float a0 = masker[((t * 3 + 0) * NFEAT + f) * NFEAT + g];
      float a1 = masker[((t * 3 + 1) * NFEAT + f) * NFEAT + g];
      float a2 = masker[((t * 3 + 2) * NFEAT + f) * NFEAT + g];
      float prod = a0 * a1 * a2;
      val = prod > 0.f ? prod : 0.f;            // relu
    }
    float s = val;
    for (int off = 32; off > 0; off >>= 1) s += __shfl_xor(s, off);
    float mean = s / (float)NFEAT;
    float d = fv ? (val - mean) : 0.f;
    float v2 = d * d;
    for (int off = 32; off > 0; off >>= 1) v2 += __shfl_xor(v2, off);
    float var = v2 / (float)NFEAT;
    float lw = fv ? ln_w[f] : 0.f;
    float lb = fv ? ln_b[f] : 0.f;
    float aln = d * rsqrtf(var + LN_EPS) * lw + lb;
    float logit = aln + ((val != 0.f) ? 0.f : NEG_INF_C) + ((f == g) ? 1.f : 0.f);
    if (!fv) logit = -3.0e38f;
    float mx = logit;
    for (int off = 32; off > 0; off >>= 1) mx = fmaxf(mx, __shfl_xor(mx, off));
    float ex = fv ? expf(logit - mx) : 0.f;
    float se = ex;
    for (int off = 32; off > 0; off >>= 1) se += __shfl_xor(se, off);
    float attn = (fv && g < NFEAT && val != 0.f) ? (ex / se) : 0.f;
    // swizzled A-frag layout: row (t*64+g), chunk (f>>3)^(g&7), elem f&7
    ws_attnTs[(t * 64 + g) * 64 + (((f >> 3) ^ (g & 7)) << 3) + (f & 7)] = (bf16_t)attn;
    ws_attnF[(t * 64 + f) * 64 + g] = attn;    // f-major copy for prep2
  }
}

// prep2 (R5/R7-verified): G_t[f][k] = V + Y,  V[f,k]=sum_e gw[f,e]W1_t[k,e],
// Y[f,k]=sum_g attn_t[f,g]*R[g,k], R[g,k]=sum_e gw[g,e]W2_t[k,e].
__global__ __launch_bounds__(256) void prep2_kernel(
    const float* __restrict__ tw, const float* __restrict__ gw,
    const float* __restrict__ ws_attnF, float* __restrict__ ws_G)
{
  __shared__ bf16_t sRT[64 * 72];
  const int t = blockIdx.x;
  const int tid = threadIdx.x;
  const int w = tid >> 6;
  const int lane = tid & 63;
  const int l16 = lane & 15;
  const int lquad = lane >> 4;
  const int fr = w * 16 + l16;
  const bool frv = (fr < NFEAT);

  bf16x8 ag[2];
#pragma unroll
  for (int kc = 0; kc < 2; ++kc) {
#pragma unroll
    for (int j = 0; j < 8; ++j) ag[kc][j] = (bf16_t)0.f;
    if (frv) {
      const float* p = gw + fr * 64 + kc * 32 + lquad * 8;
      const f32x4 r0 = *(const f32x4*)(p);
      const f32x4 r1 = *(const f32x4*)(p + 4);
#pragma unroll
      for (int j = 0; j < 4; ++j) { ag[kc][j] = (bf16_t)r0[j]; ag[kc][j+4] = (bf16_t)r1[j]; }
    }
  }

  f32x4 accR[4];
#pragma unroll
  for (int n = 0; n < 4; ++n) accR[n] = (f32x4){0.f,0.f,0.f,0.f};
#pragma unroll
  for (int kc = 0; kc < 2; ++kc)
#pragma unroll
    for (int n = 0; n < 4; ++n) {
      const float* p = tw + ((2*t+1)*64 + n*16 + l16) * 64 + kc*32 + lquad*8;
      const f32x4 r0 = *(const f32x4*)(p);
      const f32x4 r1 = *(const f32x4*)(p + 4);
      bf16x8 bw;
#pragma unroll
      for (int j = 0; j < 4; ++j) { bw[j] = (bf16_t)r0[j]; bw[j+4] = (bf16_t)r1[j]; }
      accR[n] = MFMA(ag[kc], bw, accR[n], 0, 0, 0);
    }
#pragma unroll
  for (int n = 0; n < 4; ++n) {
    bf16x4 pv;
    pv[0]=(bf16_t)accR[n][0]; pv[1]=(bf16_t)accR[n][1];
    pv[2]=(bf16_t)accR[n][2]; pv[3]=(bf16_t)accR[n][3];
    *(bf16x4*)&sRT[(n*16 + l16) * 72 + w*16 + lquad*4] = pv;
  }

  f32x4 acc[4];
#pragma unroll
  for (int n = 0; n < 4; ++n) acc[n] = (f32x4){0.f,0.f,0.f,0.f};
#pragma unroll
  for (int kc = 0; kc < 2; ++kc)
#pragma unroll
    for (int n = 0; n < 4; ++n) {
      const float* p = tw + ((2*t)*64 + n*16 + l16) * 64 + kc*32 + lquad*8;
      const f32x4 r0 = *(const f32x4*)(p);
      const f32x4 r1 = *(const f32x4*)(p + 4);
      bf16x8 bw;
#pragma unroll
      for (int j = 0; j < 4; ++j) { bw[j] = (bf16_t)r0[j]; bw[j+4] = (bf16_t)r1[j]; }
      acc[n] = MFMA(ag[kc], bw, acc[n], 0, 0, 0);
    }

  __syncthreads();

  bf16x8 aa[2];
#pragma unroll
  for (int kc = 0; kc < 2; ++kc) {
    const float* p = ws_attnF + (t*64 + fr) * 64 + kc*32 + lquad*8;
    const f32x4 r0 = *(const f32x4*)(p);
    const f32x4 r1 = *(const f32x4*)(p + 4);
#pragma unroll
    for (int j = 0; j < 4; ++j) { aa[kc][j] = (bf16_t)r0[j]; aa[kc][j+4] = (bf16_t)r1[j]; }
  }
#pragma unroll
  for (int kc = 0; kc < 2; ++kc)
#pragma unroll
    for (int n = 0; n < 4; ++n) {
      const bf16x8 bp = *(const bf16x8*)(&sRT[(n*16 + l16) * 72 + kc*32 + lquad*8]);
      acc[n] = MFMA(aa[kc], bp, acc[n], 0, 0, 0);
    }

#pragma unroll
  for (int n = 0; n < 4; ++n)
#pragma unroll
    for (int r = 0; r < 4; ++r)
      ws_G[t*4096 + (w*16 + lquad*4 + r) * 64 + n*16 + l16] = acc[n][r];
}

// BARRIER-FREE main: one wave = one whole batch. Per-wave private sPT slice
// makes the P-transpose an intra-wave write->read (in-order DS + lgkmcnt, no
// barrier). G-gate (R7-validated) makes gates per-wave (intra-wave shfl only).
// t processed sequentially reusing one 64-reg acc (P -> H -> +pass2), folded
// into accF as ga_t*acc in f32 (same math as R6 epilogue). Only barrier:
// one __syncthreads after sWT/sAT staging. Global loads/stores never drained.
__global__ __launch_bounds__(256) void main_kernel(
    const float* __restrict__ feat, const float* __restrict__ gb,
    const bf16_t* __restrict__ ws_attnTs, const bf16_t* __restrict__ ws_WT,
    const float* __restrict__ ws_tbT, const float* __restrict__ ws_G,
    const float* __restrict__ ws_cst,
    float* __restrict__ out)
{
  __shared__ bf16_t sWT[4 * 4096];   // 32 KB swizzled weights
  __shared__ bf16_t sAT[2 * 4096];   // 16 KB swizzled attnT (A-frag ready)
  __shared__ bf16_t sPT[4][4096];    // 32 KB: 8 KB private P^T per wave

  const int tid = threadIdx.x;
  const int w = tid >> 6;
  const int lane = tid & 63;
  const int l16 = lane & 15;
  const int lquad = lane >> 4;
  const int exl = l16 & 7;

  // ---- stage sWT + sAT (linear copies; globals pre-swizzled) ----
#pragma unroll
  for (int it = 0; it < 8; ++it) {
    const int idx = it * 256 + tid;
    *(bf16x8*)&sWT[idx * 8] = *(const bf16x8*)(ws_WT + idx * 8);
  }
#pragma unroll
  for (int it = 0; it < 4; ++it) {
    const int idx = it * 256 + tid;
    *(bf16x8*)&sAT[idx * 8] = *(const bf16x8*)(ws_attnTs + idx * 8);
  }
  __syncthreads();                   // the ONLY block-wide barrier

  const float cst0 = ws_cst[0], cst1 = ws_cst[1], gbv = gb[0];
  bf16_t* const myPT = &sPT[w][0];

#pragma unroll 1
  for (int ibw = 0; ibw < NBW; ++ibw) {
    const int b = blockIdx.x * (4 * NBW) + w * NBW + ibw;
    const float* featb = feat + (long)b * (NFEAT * EDIM);

    // ---- full F for this batch: rows m*16+l16 ----
    f32x4 raw[4][4];
#pragma unroll
    for (int m = 0; m < 4; ++m) {
      const int frow = m * 16 + l16;
      if (frow < NFEAT) {
        const float* p = featb + frow * 64 + lquad * 8;
        raw[m][0] = *(const f32x4*)(p);
        raw[m][1] = *(const f32x4*)(p + 4);
        raw[m][2] = *(const f32x4*)(p + 32);
        raw[m][3] = *(const f32x4*)(p + 36);
      } else {
        raw[m][0] = raw[m][1] = raw[m][2] = raw[m][3] = (f32x4){0.f,0.f,0.f,0.f};
      }
    }

    // ---- gates: logit_t = <F, G_t> + cst_t + gb (intra-wave reduce only) ----
    float p0 = 0.f, p1 = 0.f;
#pragma unroll
    for (int m = 0; m < 4; ++m) {
      const int go = (m * 16 + l16) * 64 + lquad * 8;
#pragma unroll
      for (int q = 0; q < 4; ++q) {
        const int qo = (q >> 1) * 32 + (q & 1) * 4;   // 0,4,32,36
        const f32x4 gv0 = *(const f32x4*)(ws_G + go + qo);
        const f32x4 gv1 = *(const f32x4*)(ws_G + 4096 + go + qo);
#pragma unroll
        for (int j = 0; j < 4; ++j) {
          p0 += raw[m][q][j] * gv0[j];
          p1 += raw[m][q][j] * gv1[j];
        }
      }
    }
#pragma unroll
    for (int off = 32; off > 0; off >>= 1) {
      p0 += __shfl_xor(p0, off);
      p1 += __shfl_xor(p1, off);
    }
    const float g0 = p0 + cst0 + gbv;
    const float g1 = p1 + cst1 + gbv;
    const float mx = fmaxf(g0, g1);
    const float e0 = expf(g0 - mx), e1 = expf(g1 - mx);
    const float inv = 1.f / (e0 + e1);
    const float ga0 = e0 * inv, ga1 = e1 * inv;

    // ---- bf16 A-frags (raw dies here) ----
    bf16x8 a[2][4];
#pragma unroll
    for (int m = 0; m < 4; ++m)
#pragma unroll
      for (int kc = 0; kc < 2; ++kc)
#pragma unroll
        for (int j = 0; j < 4; ++j) {
          a[kc][m][j]     = (bf16_t)raw[m][kc * 2][j];
          a[kc][m][j + 4] = (bf16_t)raw[m][kc * 2 + 1][j];
        }

    f32x4 accF[4][4];

#pragma unroll
    for (int t = 0; t < 2; ++t) {
      const float gat = (t == 0) ? ga0 : ga1;
      f32x4 acc[4][4];

      // P = F @ W2_t
#pragma unroll
      for (int m = 0; m < 4; ++m)
#pragma unroll
        for (int n = 0; n < 4; ++n) acc[m][n] = (f32x4){0.f,0.f,0.f,0.f};
#pragma unroll
      for (int kc = 0; kc < 2; ++kc) {
        const int co = ((kc * 4 + lquad) ^ exl) * 8;
#pragma unroll
        for (int n = 0; n < 4; ++n) {
          const bf16x8 bw = *(const bf16x8*)(&sWT[(2 * t + 1) * 4096 + (n * 16 + l16) * 64 + co]);
#pragma unroll
          for (int m = 0; m < 4; ++m)
            acc[m][n] = MFMA(a[kc][m], bw, acc[m][n], 0, 0, 0);
        }
      }

      // write P^T (swizzled, private slice; same-wave in-order DS)
#pragma unroll
      for (int m = 0; m < 4; ++m) {
        const int wch = (((m * 2 + (lquad >> 1)) ^ exl) << 3) + (lquad & 1) * 4;
#pragma unroll
        for (int n = 0; n < 4; ++n) {
          bf16x4 pv;
          pv[0] = (bf16_t)acc[m][n][0]; pv[1] = (bf16_t)acc[m][n][1];
          pv[2] = (bf16_t)acc[m][n][2]; pv[3] = (bf16_t)acc[m][n][3];
          *(bf16x4*)&myPT[(n * 16 + l16) * 64 + wch] = pv;
        }
      }

      // H = F @ W1_t (independent MFMAs fill the P write->read gap)
#pragma unroll
      for (int m = 0; m < 4; ++m)
#pragma unroll
        for (int n = 0; n < 4; ++n) acc[m][n] = (f32x4){0.f,0.f,0.f,0.f};
#pragma unroll
      for (int kc = 0; kc < 2; ++kc) {
        const int co = ((kc * 4 + lquad) ^ exl) * 8;
#pragma unroll
        for (int n = 0; n < 4; ++n) {
          const bf16x8 bw = *(const bf16x8*)(&sWT[(2 * t) * 4096 + (n * 16 + l16) * 64 + co]);
#pragma unroll
          for (int m = 0; m < 4; ++m)
            acc[m][n] = MFMA(a[kc][m], bw, acc[m][n], 0, 0, 0);
        }
      }

      // H += attnT_t @ P_t (A from sAT, B from private sPT; both swizzled)
#pragma unroll
      for (int kc = 0; kc < 2; ++kc) {
        const int co = ((kc * 4 + lquad) ^ exl) * 8;
        bf16x8 aat[4];
#pragma unroll
        for (int m = 0; m < 4; ++m)
          aat[m] = *(const bf16x8*)(&sAT[t * 4096 + (m * 16 + l16) * 64 + co]);
#pragma unroll
        for (int n = 0; n < 4; ++n) {
          const bf16x8 bp = *(const bf16x8*)(&myPT[(n * 16 + l16) * 64 + co]);
#pragma unroll
          for (int m = 0; m < 4; ++m)
            acc[m][n] = MFMA(aat[m], bp, acc[m][n], 0, 0, 0);
        }
      }

      // fold with gate (f32; same math as R6's epilogue combine)
#pragma unroll
      for (int m = 0; m < 4; ++m)
#pragma unroll
        for (int n = 0; n < 4; ++n)
#pragma unroll
          for (int r = 0; r < 4; ++r) {
            if (t == 0) accF[m][n][r]  = gat * acc[m][n][r];
            else        accF[m][n][r] += gat * acc[m][n][r];
          }
    }

    // ---- epilogue: + ga0*tb0 + ga1*tb1, store ----
    float* outb = out + (long)b * (NFEAT * EDIM);
#pragma unroll
    for (int m = 0; m < 4; ++m) {
#pragma unroll
      for (int n = 0; n < 4; ++n) {
        const int ro = (n * 16 + l16) * 64 + m * 16 + lquad * 4;
        const f32x4 tbv0 = *(const f32x4*)(ws_tbT + ro);
        const f32x4 tbv1 = *(const f32x4*)(ws_tbT + 4096 + ro);
        const int e = n * 16 + l16;
#pragma unroll
        for (int r = 0; r < 4; ++r) {
          const int f = m * 16 + lquad * 4 + r;
          if (f < NFEAT)
            outb[f * 64 + e] = accF[m][n][r] + ga0 * tbv0[r] + ga1 * tbv1[r];
        }
      }
    }
  }
}

extern "C" void kernel_launch(void* const* d_in, const int* in_sizes, int n_in,
                              void* d_out, int out_size, void* d_ws, size_t ws_size,
                              hipStream_t stream) {
  const float* feat   = (const float*)d_in[0];
  const float* masker = (const float*)d_in[1];
  const float* tw     = (const float*)d_in[2];
  const float* tb     = (const float*)d_in[3];
  const float* lnw    = (const float*)d_in[4];
  const float* lnb    = (const float*)d_in[5];
  const float* gw     = (const float*)d_in[6];
  const float* gb     = (const float*)d_in[7];
  float* out = (float*)d_out;

  bf16_t* ws_attnTs = (bf16_t*)d_ws;                  // 8192 bf16 (swizzled)
  bf16_t* ws_WT     = ws_attnTs + 8192;               // 16384 bf16
  float*  ws_tbT    = (float*)(ws_WT + 16384);        // 8192 f32
  float*  ws_attnF  = ws_tbT + 8192;                  // 8192 f32
  float*  ws_G      = ws_attnF + 8192;                // 8192 f32
  float*  ws_cst    = ws_G + 8192;                    // 2 f32

  prep_kernel<<<16, 256, 0, stream>>>(masker, lnw, lnb, tw, tb, gw,
                                      ws_attnTs, ws_WT, ws_tbT, ws_attnF, ws_cst);
  prep2_kernel<<<2, 256, 0, stream>>>(tw, gw, ws_attnF, ws_G);
  main_kernel<<<4096 / (4 * NBW), 256, 0, stream>>>(feat, gb, ws_attnTs, ws_WT,
                                                    ws_tbT, ws_G, ws_cst, out);
}